// Round 1
// 194.722 us; speedup vs baseline: 1.0197x; 1.0197x over previous
//
#include <hip/hip_runtime.h>

#define SEQ   2048
#define NBATCH 8
#define EMB   1024
#define HD    64
#define QKVSZ (NBATCH * SEQ * HD)   /* 1048576 elems per matrix */
#define WTSZ  (3 * HD * EMB)        /* 196608 */
#define KSTR  72
#define VSTR  72
#define PSTR  72                    /* >=64 + 16B-aligned (R9 bug was 40) */
#define PSLOT 1088                  /* floats per partial slot: 1024 O + 16 m + 16 l + pad */

typedef __attribute__((ext_vector_type(8))) short bf16x8;
typedef __attribute__((ext_vector_type(4))) float f32x4;

__device__ inline unsigned short f2b(float f) {
  union { float f; unsigned int i; } u; u.f = f;
  unsigned int r = (u.i + 0x7FFFu + ((u.i >> 16) & 1u)) >> 16;  // RNE
  return (unsigned short)r;
}

// ---------------- W transpose (R10 proven, verbatim) ----------------
__global__ __launch_bounds__(256) void wtrans_kernel(const float* __restrict__ wq,
                                                     const float* __restrict__ wk,
                                                     const float* __restrict__ wv,
                                                     unsigned short* __restrict__ wt) {
  int i = blockIdx.x * 256 + threadIdx.x;       // 0 .. 196607
  int m = i >> 16;
  int c = (i >> 10) & 63;
  int d = i & 1023;
  const float* src = (m == 0) ? wq : ((m == 1) ? wk : wv);
  wt[i] = f2b(src[d * 64 + c]);
}

// ---------------- QKV projection: split-K x4, LDS cross-wave reduce ----------------
// grid = 1024 blocks (4 blocks/CU = 16 waves/CU = 4 waves/SIMD).
// Each block owns ONE 16-row tile; wave w reduces K-chunk [w*256, w*256+256).
__global__ __launch_bounds__(256, 4) void qkv_proj_kernel(const float* __restrict__ emb,
                                                          const unsigned short* __restrict__ wt,
                                                          unsigned short* __restrict__ qkv) {
  // waves 1..3 park their 12 f32x4 partials here; wave 0 sums. 3*12*64*4*4B = 36 KB
  __shared__ __align__(16) float red[3][12 * 64 * 4];

  const int t = threadIdx.x;
  const int wave = t >> 6;          // K-chunk index 0..3
  const int lane = t & 63;
  const int quad = lane >> 4;
  const int l16  = lane & 15;
  const int rt   = blockIdx.x;      // row tile 0..1023
  const int k0   = wave * 256;

  const float* arow = emb + ((size_t)(rt * 16 + l16)) * EMB + k0 + quad * 8;
  const unsigned short* wbase = wt + (size_t)l16 * EMB + k0 + quad * 8;

  f32x4 acc[3][4];
#pragma unroll
  for (int m = 0; m < 3; m++)
#pragma unroll
    for (int n = 0; n < 4; n++) acc[m][n] = (f32x4){0.f, 0.f, 0.f, 0.f};

#pragma unroll
  for (int i = 0; i < 8; i++) {                 // 8 k-steps of 32 = K-chunk 256
    f32x4 a0 = *(const f32x4*)(arow + i * 32);
    f32x4 a1 = *(const f32x4*)(arow + i * 32 + 4);
    bf16x8 af;
#pragma unroll
    for (int j = 0; j < 4; j++) {
      af[j]     = (short)f2b(a0[j]);
      af[4 + j] = (short)f2b(a1[j]);
    }
#pragma unroll
    for (int m = 0; m < 3; m++)
#pragma unroll
      for (int nt = 0; nt < 4; nt++) {
        bf16x8 bf = *(const bf16x8*)(wbase + m * 65536 + (size_t)nt * 16 * EMB + i * 32);
        acc[m][nt] = __builtin_amdgcn_mfma_f32_16x16x32_bf16(af, bf, acc[m][nt], 0, 0, 0);
      }
  }

  if (wave > 0) {
#pragma unroll
    for (int m = 0; m < 3; m++)
#pragma unroll
      for (int nt = 0; nt < 4; nt++)
        *(f32x4*)&red[wave - 1][(m * 4 + nt) * 256 + lane * 4] = acc[m][nt];
  }
  __syncthreads();
  if (wave == 0) {
#pragma unroll
    for (int m = 0; m < 3; m++)
#pragma unroll
      for (int nt = 0; nt < 4; nt++) {
        f32x4 r0 = *(const f32x4*)&red[0][(m * 4 + nt) * 256 + lane * 4];
        f32x4 r1 = *(const f32x4*)&red[1][(m * 4 + nt) * 256 + lane * 4];
        f32x4 r2 = *(const f32x4*)&red[2][(m * 4 + nt) * 256 + lane * 4];
        acc[m][nt] = acc[m][nt] + r0 + r1 + r2;
      }
#pragma unroll
    for (int m = 0; m < 3; m++)
#pragma unroll
      for (int nt = 0; nt < 4; nt++)
#pragma unroll
        for (int r = 0; r < 4; r++) {
          int row = rt * 16 + quad * 4 + r;     // C/D: row = quad*4+reg, col = l16
          qkv[(size_t)m * QKVSZ + (size_t)row * HD + nt * 16 + l16] = f2b(acc[m][nt][r]);
        }
  }
}

// ---------------- Split-K flash attention: 1 wave/block, 16 q-rows, <=16-tile chunks --------
// grid.x = 192: idx<128 -> (qt=idx, c=0); idx>=128 -> (qt=64+idx-128, c=1)
__global__ __launch_bounds__(64, 2) void attn_split(const unsigned short* __restrict__ qkv,
                                                    float* __restrict__ part,
                                                    float* __restrict__ out) {
  __shared__ __align__(16) unsigned short Ksh[64 * KSTR];
  __shared__ __align__(16) unsigned short Vt[64 * VSTR];      // Vt[h][key]
  __shared__ __align__(16) unsigned short Psh[16 * PSTR];

  const int t = threadIdx.x;        // one wave
  const int quad = t >> 4;
  const int l16  = t & 15;
  const int idx = blockIdx.x;
  const int b   = blockIdx.y;
  const int qt  = (idx < 128) ? idx : (64 + (idx - 128));
  const int c   = (idx < 128) ? 0 : 1;
  const int q0  = qt * 16;
  const int kdiag = qt >> 2;                      // global diagonal tile
  const int t0 = c * 16;
  const int t1 = (c == 0) ? min(15, kdiag) : kdiag;

  const unsigned short* qg = qkv;
  const unsigned short* kg = qkv + QKVSZ;
  const unsigned short* vg = qkv + 2 * QKVSZ;

  const unsigned short* qptr = qg + ((size_t)(b * SEQ + q0 + l16)) * HD + quad * 8;
  const bf16x8 qf0 = *(const bf16x8*)qptr;        // d 0..31
  const bf16x8 qf1 = *(const bf16x8*)(qptr + 32); // d 32..63

  f32x4 o0 = {0,0,0,0}, o1 = {0,0,0,0}, o2 = {0,0,0,0}, o3 = {0,0,0,0};
  float mst[4] = {-INFINITY, -INFINITY, -INFINITY, -INFINITY};
  float lst[4] = {0.f, 0.f, 0.f, 0.f};
  const float sc = 0.125f * 1.44269504088896f;    // 1/sqrt(64) * log2(e)

  // prologue: prefetch tile t0 into registers
  bf16x8 kpre[8], vpre[8];
  {
    const bf16x8* ks = (const bf16x8*)(kg + ((size_t)(b * SEQ + t0 * 64)) * HD);
#pragma unroll
    for (int i = 0; i < 8; i++) kpre[i] = ks[t + i * 64];
    const bf16x8* vs = (const bf16x8*)(vg + ((size_t)(b * SEQ + t0 * 64 + t)) * HD);
#pragma unroll
    for (int i = 0; i < 8; i++) vpre[i] = vs[i];   // full row of key t0*64+t
  }

  for (int kb = t0; kb <= t1; kb++) {
    // stage prefetched tile into LDS
#pragma unroll
    for (int i = 0; i < 8; i++) {
      int u = t + i * 64;                          // 0..511 16B-units
      *(bf16x8*)(Ksh + (u >> 3) * KSTR + (u & 7) * 8) = kpre[i];
    }
#pragma unroll
    for (int i = 0; i < 8; i++)
#pragma unroll
      for (int j = 0; j < 8; j++)
        Vt[(i * 8 + j) * VSTR + t] = (unsigned short)vpre[i][j];  // Vt[h][key=t]
    __syncthreads();

    // prefetch next tile
    if (kb < t1) {
      const bf16x8* ks = (const bf16x8*)(kg + ((size_t)(b * SEQ + (kb + 1) * 64)) * HD);
#pragma unroll
      for (int i = 0; i < 8; i++) kpre[i] = ks[t + i * 64];
      const bf16x8* vs = (const bf16x8*)(vg + ((size_t)(b * SEQ + (kb + 1) * 64 + t)) * HD);
#pragma unroll
      for (int i = 0; i < 8; i++) vpre[i] = vs[i];
    }

    // S = Q K^T  (4 ktiles of 16 keys)
    f32x4 s[4];
#pragma unroll
    for (int kt = 0; kt < 4; kt++) {
      bf16x8 kf0 = *(const bf16x8*)(Ksh + (kt * 16 + l16) * KSTR + quad * 8);
      bf16x8 kf1 = *(const bf16x8*)(Ksh + (kt * 16 + l16) * KSTR + 32 + quad * 8);
      f32x4 z = {0.f, 0.f, 0.f, 0.f};
      z = __builtin_amdgcn_mfma_f32_16x16x32_bf16(qf0, kf0, z, 0, 0, 0);
      z = __builtin_amdgcn_mfma_f32_16x16x32_bf16(qf1, kf1, z, 0, 0, 0);
      s[kt] = z;
    }

    // scale; causal mask only on the diagonal tile
    if (kb == kdiag) {
#pragma unroll
      for (int r = 0; r < 4; r++) {
        int rowg = q0 + quad * 4 + r;
#pragma unroll
        for (int kt = 0; kt < 4; kt++) {
          int col = kb * 64 + kt * 16 + l16;
          float v = s[kt][r] * sc;
          s[kt][r] = (col > rowg) ? -INFINITY : v;
        }
      }
    } else {
#pragma unroll
      for (int r = 0; r < 4; r++)
#pragma unroll
        for (int kt = 0; kt < 4; kt++) s[kt][r] *= sc;
    }

    // online softmax (reduce across the 16-lane col group)
    float alpha[4];
#pragma unroll
    for (int r = 0; r < 4; r++) {
      float mx = fmaxf(fmaxf(s[0][r], s[1][r]), fmaxf(s[2][r], s[3][r]));
#pragma unroll
      for (int off = 1; off < 16; off <<= 1) mx = fmaxf(mx, __shfl_xor(mx, off, 64));
      float mnew = fmaxf(mst[r], mx);
      alpha[r] = exp2f(mst[r] - mnew);
      mst[r] = mnew;
    }
#pragma unroll
    for (int r = 0; r < 4; r++) {
      float sm = 0.f;
#pragma unroll
      for (int kt = 0; kt < 4; kt++) {
        float p = exp2f(s[kt][r] - mst[r]);
        s[kt][r] = p;
        sm += p;
      }
#pragma unroll
      for (int off = 1; off < 16; off <<= 1) sm += __shfl_xor(sm, off, 64);
      lst[r] = lst[r] * alpha[r] + sm;
    }
#pragma unroll
    for (int r = 0; r < 4; r++) { o0[r] *= alpha[r]; o1[r] *= alpha[r]; o2[r] *= alpha[r]; o3[r] *= alpha[r]; }

    // P (C-layout) -> LDS bf16
#pragma unroll
    for (int kt = 0; kt < 4; kt++)
#pragma unroll
      for (int r = 0; r < 4; r++)
        Psh[(quad * 4 + r) * PSTR + kt * 16 + l16] = f2b(s[kt][r]);
    __syncthreads();

    // O += P V
#pragma unroll
    for (int kc = 0; kc < 2; kc++) {
      bf16x8 pf = *(const bf16x8*)(Psh + l16 * PSTR + kc * 32 + quad * 8);
      bf16x8 vf0 = *(const bf16x8*)(Vt + (0 + l16) * VSTR + kc * 32 + quad * 8);
      bf16x8 vf1 = *(const bf16x8*)(Vt + (16 + l16) * VSTR + kc * 32 + quad * 8);
      bf16x8 vf2 = *(const bf16x8*)(Vt + (32 + l16) * VSTR + kc * 32 + quad * 8);
      bf16x8 vf3 = *(const bf16x8*)(Vt + (48 + l16) * VSTR + kc * 32 + quad * 8);
      o0 = __builtin_amdgcn_mfma_f32_16x16x32_bf16(pf, vf0, o0, 0, 0, 0);
      o1 = __builtin_amdgcn_mfma_f32_16x16x32_bf16(pf, vf1, o1, 0, 0, 0);
      o2 = __builtin_amdgcn_mfma_f32_16x16x32_bf16(pf, vf2, o2, 0, 0, 0);
      o3 = __builtin_amdgcn_mfma_f32_16x16x32_bf16(pf, vf3, o3, 0, 0, 0);
    }
    __syncthreads();
  }

  if (qt < 64) {  // single chunk: finalize directly
#pragma unroll
    for (int r = 0; r < 4; r++) {
      float inv = 1.f / lst[r];
      int rowg = q0 + quad * 4 + r;
      size_t ob = ((size_t)(b * SEQ + rowg)) * HD + l16;
      out[ob + 0]  = o0[r] * inv;
      out[ob + 16] = o1[r] * inv;
      out[ob + 32] = o2[r] * inv;
      out[ob + 48] = o3[r] * inv;
    }
  } else {        // write unnormalized partial + (m,l)
    float* ps = part + ((size_t)((b * 64 + (qt - 64)) * 2 + c)) * PSLOT;
#pragma unroll
    for (int r = 0; r < 4; r++) {
      int row = quad * 4 + r;
      ps[row * 64 + 0  + l16] = o0[r];
      ps[row * 64 + 16 + l16] = o1[r];
      ps[row * 64 + 32 + l16] = o2[r];
      ps[row * 64 + 48 + l16] = o3[r];
      if (l16 == 0) {
        ps[1024 + row] = mst[r];
        ps[1040 + row] = lst[r];
      }
    }
  }
}

// ---------------- merge two partials for qt in [64,128) ----------------
__global__ __launch_bounds__(64) void attn_merge(const float* __restrict__ part,
                                                 float* __restrict__ out) {
  const int h  = threadIdx.x;       // 0..63
  const int qx = blockIdx.x;        // 0..63 -> qt = 64+qx
  const int b  = blockIdx.y;
  const float* p0 = part + ((size_t)((b * 64 + qx) * 2 + 0)) * PSLOT;
  const float* p1 = p0 + PSLOT;
#pragma unroll 4
  for (int r = 0; r < 16; r++) {
    float m0 = p0[1024 + r], l0 = p0[1040 + r];
    float m1 = p1[1024 + r], l1 = p1[1040 + r];
    float M  = fmaxf(m0, m1);
    float e0 = exp2f(m0 - M), e1 = exp2f(m1 - M);
    float L  = l0 * e0 + l1 * e1;
    float o  = (p0[r * 64 + h] * e0 + p1[r * 64 + h] * e1) / L;
    out[((size_t)(b * SEQ + (64 + qx) * 16 + r)) * HD + h] = o;
  }
}

extern "C" void kernel_launch(void* const* d_in, const int* in_sizes, int n_in,
                              void* d_out, int out_size, void* d_ws, size_t ws_size,
                              hipStream_t stream) {
  const float* emb = (const float*)d_in[0];
  const float* wq  = (const float*)d_in[1];
  const float* wk  = (const float*)d_in[2];
  const float* wv  = (const float*)d_in[3];
  unsigned short* ws  = (unsigned short*)d_ws;
  unsigned short* wt  = ws;              // 196608 bf16
  unsigned short* qkv = ws + WTSZ;       // 3 x 1048576 bf16
  float* part = (float*)(ws + WTSZ + 3 * QKVSZ);   // 1024 slots x 1088 fp32 = 4.25 MB

  hipLaunchKernelGGL(wtrans_kernel,   dim3(WTSZ / 256), dim3(256), 0, stream, wq, wk, wv, wt);
  hipLaunchKernelGGL(qkv_proj_kernel, dim3(1024),       dim3(256), 0, stream, emb, wt, qkv);
  hipLaunchKernelGGL(attn_split,      dim3(192, 8),     dim3(64),  0, stream, qkv, part, (float*)d_out);
  hipLaunchKernelGGL(attn_merge,      dim3(64, 8),      dim3(64),  0, stream, part, (float*)d_out);
}

// Round 2
// 170.576 us; speedup vs baseline: 1.1641x; 1.1416x over previous
//
#include <hip/hip_runtime.h>

#define SEQ   2048
#define NBATCH 8
#define EMB   1024
#define HD    64
#define QKVSZ (NBATCH * SEQ * HD)   /* 1048576 elems per matrix */
#define WTSZ  (3 * HD * EMB)        /* 196608 */
#define KSTR  72
#define VSTR  72
#define PSTR  72                    /* >=64 + 16B-aligned (R9 bug was 40) */
#define PSLOT 1088                  /* floats per partial slot: 1024 O + 16 m + 16 l + pad */

typedef __attribute__((ext_vector_type(8))) short bf16x8;
typedef __attribute__((ext_vector_type(4))) float f32x4;

__device__ inline unsigned short f2b(float f) {
  union { float f; unsigned int i; } u; u.f = f;
  unsigned int r = (u.i + 0x7FFFu + ((u.i >> 16) & 1u)) >> 16;  // RNE
  return (unsigned short)r;
}

// ---------------- W transpose -> K-blocked layout [kb][m][c][kd] ----------------
// chunk kb (64 K-values) is contiguous: 3*64*64 = 12288 bf16 = 24576 B
__global__ __launch_bounds__(256) void wtrans_kernel(const float* __restrict__ wq,
                                                     const float* __restrict__ wk,
                                                     const float* __restrict__ wv,
                                                     unsigned short* __restrict__ wt) {
  int i = blockIdx.x * 256 + threadIdx.x;       // 0 .. 196607
  int kb  = i / 12288;
  int rem = i - kb * 12288;
  int m   = rem >> 12;          // 0..2
  int c   = (rem >> 6) & 63;    // output col within head
  int kd  = rem & 63;           // k within block
  const float* src = (m == 0) ? wq : ((m == 1) ? wk : wv);
  int d = kb * 64 + kd;
  wt[i] = f2b(src[d * 64 + c]);
}

// ---------------- QKV projection: LDS-staged tiled GEMM ----------------
// [16384 x 1024] fp32  x  [1024 x 192] bf16.  BM=32, BN=96 (col-half), BK=64.
// grid = 512 row-tiles x 2 col-halves = 1024 blocks -> 4 blocks/CU -> 16 waves/CU.
// Double-buffered LDS (32 KB) + register prefetch; XOR-swizzled tiles so
// ds_read_b128 fragment reads are bank-conflict-free.
__global__ __launch_bounds__(256, 4) void qkv_proj_kernel(const float* __restrict__ emb,
                                                          const unsigned short* __restrict__ wt,
                                                          unsigned short* __restrict__ qkv) {
  __shared__ __align__(16) unsigned short Ab[2][32 * 64];   // 8 KB  (row stride 128B, swizzled)
  __shared__ __align__(16) unsigned short Wb[2][96 * 64];   // 24 KB (col stride 128B, swizzled)

  const int t    = threadIdx.x;
  const int wave = t >> 6;
  const int lane = t & 63;
  const int quad = lane >> 4;
  const int l16  = lane & 15;
  const int bx = blockIdx.x;
  const int rt = bx >> 1;          // row tile (32 rows)
  const int ch = bx & 1;           // col half (96 cols)
  const int wr = wave >> 1;        // row sub-tile (16 rows)
  const int wc = wave & 1;         // col sub (48 cols = 3 MFMA tiles)

  const float* aBase = emb + (size_t)rt * 32 * EMB;
  const unsigned short* wBase = wt + ch * 6144;   // col-half offset within each kb chunk

  f32x4 acc[3];
#pragma unroll
  for (int j = 0; j < 3; j++) acc[j] = (f32x4){0.f, 0.f, 0.f, 0.f};

  f32x4 pa[2];
  bf16x8 pw[3];

  // ---- prologue: load tile kb=0 into regs, stage to buf0 ----
#pragma unroll
  for (int j = 0; j < 2; j++) {
    int u = t + j * 256;
    pa[j] = *(const f32x4*)(aBase + (size_t)(u >> 4) * EMB + (u & 15) * 4);
  }
#pragma unroll
  for (int j = 0; j < 3; j++) {
    int u = t + j * 256;
    pw[j] = *(const bf16x8*)(wBase + u * 8);
  }
#pragma unroll
  for (int j = 0; j < 2; j++) {
    int u = t + j * 256;
    int row = u >> 4, kq = u & 15;
    unsigned int lo = (unsigned int)f2b(pa[j][0]) | ((unsigned int)f2b(pa[j][1]) << 16);
    unsigned int hi = (unsigned int)f2b(pa[j][2]) | ((unsigned int)f2b(pa[j][3]) << 16);
    uint2 pk; pk.x = lo; pk.y = hi;
    *(uint2*)((char*)&Ab[0][0] + row * 128 + ((kq * 8) ^ ((row & 7) << 4))) = pk;
  }
#pragma unroll
  for (int j = 0; j < 3; j++) {
    int u = t + j * 256;
    int coll = u >> 3, kd8 = u & 7;
    *(bf16x8*)((char*)&Wb[0][0] + coll * 128 + ((kd8 ^ (coll & 7)) << 4)) = pw[j];
  }
  __syncthreads();

  // ---- main loop over 16 K-steps ----
#pragma unroll 2
  for (int kb = 0; kb < 16; kb++) {
    const int cur = kb & 1;

    // issue next tile's global loads (in flight across the compute phase)
    if (kb < 15) {
#pragma unroll
      for (int j = 0; j < 2; j++) {
        int u = t + j * 256;
        pa[j] = *(const f32x4*)(aBase + (size_t)(u >> 4) * EMB + (kb + 1) * 64 + (u & 15) * 4);
      }
#pragma unroll
      for (int j = 0; j < 3; j++) {
        int u = t + j * 256;
        pw[j] = *(const bf16x8*)(wBase + (kb + 1) * 12288 + u * 8);
      }
    }

    // compute current tile from LDS
    const int arow = wr * 16 + l16;
#pragma unroll
    for (int kh = 0; kh < 2; kh++) {
      bf16x8 af = *(const bf16x8*)((const char*)&Ab[cur][0] + arow * 128 +
                                   ((kh * 64 + quad * 16) ^ ((arow & 7) << 4)));
#pragma unroll
      for (int j = 0; j < 3; j++) {
        const int coll = (wc * 3 + j) * 16 + l16;
        bf16x8 wf = *(const bf16x8*)((const char*)&Wb[cur][0] + coll * 128 +
                                     ((kh * 64 + quad * 16) ^ ((coll & 7) << 4)));
        acc[j] = __builtin_amdgcn_mfma_f32_16x16x32_bf16(af, wf, acc[j], 0, 0, 0);
      }
    }

    // stage next tile into the other buffer
    if (kb < 15) {
      const int nb = cur ^ 1;
#pragma unroll
      for (int j = 0; j < 2; j++) {
        int u = t + j * 256;
        int row = u >> 4, kq = u & 15;
        unsigned int lo = (unsigned int)f2b(pa[j][0]) | ((unsigned int)f2b(pa[j][1]) << 16);
        unsigned int hi = (unsigned int)f2b(pa[j][2]) | ((unsigned int)f2b(pa[j][3]) << 16);
        uint2 pk; pk.x = lo; pk.y = hi;
        *(uint2*)((char*)&Ab[nb][0] + row * 128 + ((kq * 8) ^ ((row & 7) << 4))) = pk;
      }
#pragma unroll
      for (int j = 0; j < 3; j++) {
        int u = t + j * 256;
        int coll = u >> 3, kd8 = u & 7;
        *(bf16x8*)((char*)&Wb[nb][0] + coll * 128 + ((kd8 ^ (coll & 7)) << 4)) = pw[j];
      }
      __syncthreads();
    }
  }

  // ---- epilogue ----
#pragma unroll
  for (int j = 0; j < 3; j++) {
    int gc = ch * 96 + (wc * 3 + j) * 16 + l16;
    int m  = gc >> 6, cm = gc & 63;
#pragma unroll
    for (int r = 0; r < 4; r++) {
      int row = rt * 32 + wr * 16 + quad * 4 + r;   // C/D: row = quad*4+reg, col = l16
      qkv[(size_t)m * QKVSZ + (size_t)row * HD + cm] = f2b(acc[j][r]);
    }
  }
}

// ---------------- Split-K flash attention: 1 wave/block, 16 q-rows, <=16-tile chunks --------
// grid.x = 192: idx<128 -> (qt=idx, c=0); idx>=128 -> (qt=64+idx-128, c=1)
__global__ __launch_bounds__(64, 2) void attn_split(const unsigned short* __restrict__ qkv,
                                                    float* __restrict__ part,
                                                    float* __restrict__ out) {
  __shared__ __align__(16) unsigned short Ksh[64 * KSTR];
  __shared__ __align__(16) unsigned short Vt[64 * VSTR];      // Vt[h][key]
  __shared__ __align__(16) unsigned short Psh[16 * PSTR];

  const int t = threadIdx.x;        // one wave
  const int quad = t >> 4;
  const int l16  = t & 15;
  const int idx = blockIdx.x;
  const int b   = blockIdx.y;
  const int qt  = (idx < 128) ? idx : (64 + (idx - 128));
  const int c   = (idx < 128) ? 0 : 1;
  const int q0  = qt * 16;
  const int kdiag = qt >> 2;                      // global diagonal tile
  const int t0 = c * 16;
  const int t1 = (c == 0) ? min(15, kdiag) : kdiag;

  const unsigned short* qg = qkv;
  const unsigned short* kg = qkv + QKVSZ;
  const unsigned short* vg = qkv + 2 * QKVSZ;

  const unsigned short* qptr = qg + ((size_t)(b * SEQ + q0 + l16)) * HD + quad * 8;
  const bf16x8 qf0 = *(const bf16x8*)qptr;        // d 0..31
  const bf16x8 qf1 = *(const bf16x8*)(qptr + 32); // d 32..63

  f32x4 o0 = {0,0,0,0}, o1 = {0,0,0,0}, o2 = {0,0,0,0}, o3 = {0,0,0,0};
  float mst[4] = {-INFINITY, -INFINITY, -INFINITY, -INFINITY};
  float lst[4] = {0.f, 0.f, 0.f, 0.f};
  const float sc = 0.125f * 1.44269504088896f;    // 1/sqrt(64) * log2(e)

  // prologue: prefetch tile t0 into registers
  bf16x8 kpre[8], vpre[8];
  {
    const bf16x8* ks = (const bf16x8*)(kg + ((size_t)(b * SEQ + t0 * 64)) * HD);
#pragma unroll
    for (int i = 0; i < 8; i++) kpre[i] = ks[t + i * 64];
    const bf16x8* vs = (const bf16x8*)(vg + ((size_t)(b * SEQ + t0 * 64 + t)) * HD);
#pragma unroll
    for (int i = 0; i < 8; i++) vpre[i] = vs[i];   // full row of key t0*64+t
  }

  for (int kb = t0; kb <= t1; kb++) {
    // stage prefetched tile into LDS
#pragma unroll
    for (int i = 0; i < 8; i++) {
      int u = t + i * 64;                          // 0..511 16B-units
      *(bf16x8*)(Ksh + (u >> 3) * KSTR + (u & 7) * 8) = kpre[i];
    }
#pragma unroll
    for (int i = 0; i < 8; i++)
#pragma unroll
      for (int j = 0; j < 8; j++)
        Vt[(i * 8 + j) * VSTR + t] = (unsigned short)vpre[i][j];  // Vt[h][key=t]
    __syncthreads();

    // prefetch next tile
    if (kb < t1) {
      const bf16x8* ks = (const bf16x8*)(kg + ((size_t)(b * SEQ + (kb + 1) * 64)) * HD);
#pragma unroll
      for (int i = 0; i < 8; i++) kpre[i] = ks[t + i * 64];
      const bf16x8* vs = (const bf16x8*)(vg + ((size_t)(b * SEQ + (kb + 1) * 64 + t)) * HD);
#pragma unroll
      for (int i = 0; i < 8; i++) vpre[i] = vs[i];
    }

    // S = Q K^T  (4 ktiles of 16 keys)
    f32x4 s[4];
#pragma unroll
    for (int kt = 0; kt < 4; kt++) {
      bf16x8 kf0 = *(const bf16x8*)(Ksh + (kt * 16 + l16) * KSTR + quad * 8);
      bf16x8 kf1 = *(const bf16x8*)(Ksh + (kt * 16 + l16) * KSTR + 32 + quad * 8);
      f32x4 z = {0.f, 0.f, 0.f, 0.f};
      z = __builtin_amdgcn_mfma_f32_16x16x32_bf16(qf0, kf0, z, 0, 0, 0);
      z = __builtin_amdgcn_mfma_f32_16x16x32_bf16(qf1, kf1, z, 0, 0, 0);
      s[kt] = z;
    }

    // scale; causal mask only on the diagonal tile
    if (kb == kdiag) {
#pragma unroll
      for (int r = 0; r < 4; r++) {
        int rowg = q0 + quad * 4 + r;
#pragma unroll
        for (int kt = 0; kt < 4; kt++) {
          int col = kb * 64 + kt * 16 + l16;
          float v = s[kt][r] * sc;
          s[kt][r] = (col > rowg) ? -INFINITY : v;
        }
      }
    } else {
#pragma unroll
      for (int r = 0; r < 4; r++)
#pragma unroll
        for (int kt = 0; kt < 4; kt++) s[kt][r] *= sc;
    }

    // online softmax (reduce across the 16-lane col group)
    float alpha[4];
#pragma unroll
    for (int r = 0; r < 4; r++) {
      float mx = fmaxf(fmaxf(s[0][r], s[1][r]), fmaxf(s[2][r], s[3][r]));
#pragma unroll
      for (int off = 1; off < 16; off <<= 1) mx = fmaxf(mx, __shfl_xor(mx, off, 64));
      float mnew = fmaxf(mst[r], mx);
      alpha[r] = exp2f(mst[r] - mnew);
      mst[r] = mnew;
    }
#pragma unroll
    for (int r = 0; r < 4; r++) {
      float sm = 0.f;
#pragma unroll
      for (int kt = 0; kt < 4; kt++) {
        float p = exp2f(s[kt][r] - mst[r]);
        s[kt][r] = p;
        sm += p;
      }
#pragma unroll
      for (int off = 1; off < 16; off <<= 1) sm += __shfl_xor(sm, off, 64);
      lst[r] = lst[r] * alpha[r] + sm;
    }
#pragma unroll
    for (int r = 0; r < 4; r++) { o0[r] *= alpha[r]; o1[r] *= alpha[r]; o2[r] *= alpha[r]; o3[r] *= alpha[r]; }

    // P (C-layout) -> LDS bf16
#pragma unroll
    for (int kt = 0; kt < 4; kt++)
#pragma unroll
      for (int r = 0; r < 4; r++)
        Psh[(quad * 4 + r) * PSTR + kt * 16 + l16] = f2b(s[kt][r]);
    __syncthreads();

    // O += P V
#pragma unroll
    for (int kc = 0; kc < 2; kc++) {
      bf16x8 pf = *(const bf16x8*)(Psh + l16 * PSTR + kc * 32 + quad * 8);
      bf16x8 vf0 = *(const bf16x8*)(Vt + (0 + l16) * VSTR + kc * 32 + quad * 8);
      bf16x8 vf1 = *(const bf16x8*)(Vt + (16 + l16) * VSTR + kc * 32 + quad * 8);
      bf16x8 vf2 = *(const bf16x8*)(Vt + (32 + l16) * VSTR + kc * 32 + quad * 8);
      bf16x8 vf3 = *(const bf16x8*)(Vt + (48 + l16) * VSTR + kc * 32 + quad * 8);
      o0 = __builtin_amdgcn_mfma_f32_16x16x32_bf16(pf, vf0, o0, 0, 0, 0);
      o1 = __builtin_amdgcn_mfma_f32_16x16x32_bf16(pf, vf1, o1, 0, 0, 0);
      o2 = __builtin_amdgcn_mfma_f32_16x16x32_bf16(pf, vf2, o2, 0, 0, 0);
      o3 = __builtin_amdgcn_mfma_f32_16x16x32_bf16(pf, vf3, o3, 0, 0, 0);
    }
    __syncthreads();
  }

  if (qt < 64) {  // single chunk: finalize directly
#pragma unroll
    for (int r = 0; r < 4; r++) {
      float inv = 1.f / lst[r];
      int rowg = q0 + quad * 4 + r;
      size_t ob = ((size_t)(b * SEQ + rowg)) * HD + l16;
      out[ob + 0]  = o0[r] * inv;
      out[ob + 16] = o1[r] * inv;
      out[ob + 32] = o2[r] * inv;
      out[ob + 48] = o3[r] * inv;
    }
  } else {        // write unnormalized partial + (m,l)
    float* ps = part + ((size_t)((b * 64 + (qt - 64)) * 2 + c)) * PSLOT;
#pragma unroll
    for (int r = 0; r < 4; r++) {
      int row = quad * 4 + r;
      ps[row * 64 + 0  + l16] = o0[r];
      ps[row * 64 + 16 + l16] = o1[r];
      ps[row * 64 + 32 + l16] = o2[r];
      ps[row * 64 + 48 + l16] = o3[r];
      if (l16 == 0) {
        ps[1024 + row] = mst[r];
        ps[1040 + row] = lst[r];
      }
    }
  }
}

// ---------------- merge two partials for qt in [64,128) ----------------
__global__ __launch_bounds__(64) void attn_merge(const float* __restrict__ part,
                                                 float* __restrict__ out) {
  const int h  = threadIdx.x;       // 0..63
  const int qx = blockIdx.x;        // 0..63 -> qt = 64+qx
  const int b  = blockIdx.y;
  const float* p0 = part + ((size_t)((b * 64 + qx) * 2 + 0)) * PSLOT;
  const float* p1 = p0 + PSLOT;
#pragma unroll 4
  for (int r = 0; r < 16; r++) {
    float m0 = p0[1024 + r], l0 = p0[1040 + r];
    float m1 = p1[1024 + r], l1 = p1[1040 + r];
    float M  = fmaxf(m0, m1);
    float e0 = exp2f(m0 - M), e1 = exp2f(m1 - M);
    float L  = l0 * e0 + l1 * e1;
    float o  = (p0[r * 64 + h] * e0 + p1[r * 64 + h] * e1) / L;
    out[((size_t)(b * SEQ + (64 + qx) * 16 + r)) * HD + h] = o;
  }
}

extern "C" void kernel_launch(void* const* d_in, const int* in_sizes, int n_in,
                              void* d_out, int out_size, void* d_ws, size_t ws_size,
                              hipStream_t stream) {
  const float* emb = (const float*)d_in[0];
  const float* wq  = (const float*)d_in[1];
  const float* wk  = (const float*)d_in[2];
  const float* wv  = (const float*)d_in[3];
  unsigned short* ws  = (unsigned short*)d_ws;
  unsigned short* wt  = ws;              // 196608 bf16
  unsigned short* qkv = ws + WTSZ;       // 3 x 1048576 bf16
  float* part = (float*)(ws + WTSZ + 3 * QKVSZ);   // 1024 slots x 1088 fp32 = 4.25 MB

  hipLaunchKernelGGL(wtrans_kernel,   dim3(WTSZ / 256), dim3(256), 0, stream, wq, wk, wv, wt);
  hipLaunchKernelGGL(qkv_proj_kernel, dim3(1024),       dim3(256), 0, stream, emb, wt, qkv);
  hipLaunchKernelGGL(attn_split,      dim3(192, 8),     dim3(64),  0, stream, qkv, part, (float*)d_out);
  hipLaunchKernelGGL(attn_merge,      dim3(64, 8),      dim3(64),  0, stream, part, (float*)d_out);
}

// Round 3
// 161.497 us; speedup vs baseline: 1.2295x; 1.0562x over previous
//
#include <hip/hip_runtime.h>

#define SEQ   2048
#define NBATCH 8
#define EMB   1024
#define HD    64
#define QKVSZ (NBATCH * SEQ * HD)   /* 1048576 elems per matrix */
#define WTSZ  (3 * HD * EMB)        /* 196608 */
#define PSLOT 1088                  /* floats per partial slot: 1024 O + 16 m + 16 l + pad */

typedef __attribute__((ext_vector_type(8))) short bf16x8;
typedef __attribute__((ext_vector_type(4))) float f32x4;

__device__ inline unsigned short f2b(float f) {
  union { float f; unsigned int i; } u; u.f = f;
  unsigned int r = (u.i + 0x7FFFu + ((u.i >> 16) & 1u)) >> 16;  // RNE
  return (unsigned short)r;
}

// ---------------- W transpose -> K-blocked layout [kb][m][c][kd] ----------------
// chunk kb (64 K-values) is contiguous: 3*64*64 = 12288 bf16 = 24576 B
__global__ __launch_bounds__(256) void wtrans_kernel(const float* __restrict__ wq,
                                                     const float* __restrict__ wk,
                                                     const float* __restrict__ wv,
                                                     unsigned short* __restrict__ wt) {
  int i = blockIdx.x * 256 + threadIdx.x;       // 0 .. 196607
  int kb  = i / 12288;
  int rem = i - kb * 12288;
  int m   = rem >> 12;          // 0..2
  int c   = (rem >> 6) & 63;    // output col within head
  int kd  = rem & 63;           // k within block
  const float* src = (m == 0) ? wq : ((m == 1) ? wk : wv);
  int d = kb * 64 + kd;
  wt[i] = f2b(src[d * 64 + c]);
}

// ---------------- QKV projection: LDS-staged tiled GEMM ----------------
// [16384 x 1024] fp32  x  [1024 x 192] bf16.  BM=32, BN=96 (col-half), BK=64.
// Q,K stored natural [b][s][h]; V stored TRANSPOSED vT[b][h][s] via LDS epilogue
// so attn can stage it with vector copies (no per-element transpose).
__global__ __launch_bounds__(256, 4) void qkv_proj_kernel(const float* __restrict__ emb,
                                                          const unsigned short* __restrict__ wt,
                                                          unsigned short* __restrict__ qkv) {
  __shared__ __align__(16) unsigned short Ab[2][32 * 64];   // 8 KB  (row stride 128B, swizzled)
  __shared__ __align__(16) unsigned short Wb[2][96 * 64];   // 24 KB (col stride 128B, swizzled)

  const int t    = threadIdx.x;
  const int wave = t >> 6;
  const int lane = t & 63;
  const int quad = lane >> 4;
  const int l16  = lane & 15;
  const int bx = blockIdx.x;
  const int rt = bx >> 1;          // row tile (32 rows)
  const int ch = bx & 1;           // col half (96 cols)
  const int wr = wave >> 1;        // row sub-tile (16 rows)
  const int wc = wave & 1;         // col sub (48 cols = 3 MFMA tiles)

  const float* aBase = emb + (size_t)rt * 32 * EMB;
  const unsigned short* wBase = wt + ch * 6144;   // col-half offset within each kb chunk

  f32x4 acc[3];
#pragma unroll
  for (int j = 0; j < 3; j++) acc[j] = (f32x4){0.f, 0.f, 0.f, 0.f};

  f32x4 pa[2];
  bf16x8 pw[3];

  // ---- prologue: load tile kb=0 into regs, stage to buf0 ----
#pragma unroll
  for (int j = 0; j < 2; j++) {
    int u = t + j * 256;
    pa[j] = *(const f32x4*)(aBase + (size_t)(u >> 4) * EMB + (u & 15) * 4);
  }
#pragma unroll
  for (int j = 0; j < 3; j++) {
    int u = t + j * 256;
    pw[j] = *(const bf16x8*)(wBase + u * 8);
  }
#pragma unroll
  for (int j = 0; j < 2; j++) {
    int u = t + j * 256;
    int row = u >> 4, kq = u & 15;
    unsigned int lo = (unsigned int)f2b(pa[j][0]) | ((unsigned int)f2b(pa[j][1]) << 16);
    unsigned int hi = (unsigned int)f2b(pa[j][2]) | ((unsigned int)f2b(pa[j][3]) << 16);
    uint2 pk; pk.x = lo; pk.y = hi;
    *(uint2*)((char*)&Ab[0][0] + row * 128 + ((kq * 8) ^ ((row & 7) << 4))) = pk;
  }
#pragma unroll
  for (int j = 0; j < 3; j++) {
    int u = t + j * 256;
    int coll = u >> 3, kd8 = u & 7;
    *(bf16x8*)((char*)&Wb[0][0] + coll * 128 + ((kd8 ^ (coll & 7)) << 4)) = pw[j];
  }
  __syncthreads();

  // ---- main loop over 16 K-steps ----
#pragma unroll 2
  for (int kb = 0; kb < 16; kb++) {
    const int cur = kb & 1;

    // issue next tile's global loads (in flight across the compute phase)
    if (kb < 15) {
#pragma unroll
      for (int j = 0; j < 2; j++) {
        int u = t + j * 256;
        pa[j] = *(const f32x4*)(aBase + (size_t)(u >> 4) * EMB + (kb + 1) * 64 + (u & 15) * 4);
      }
#pragma unroll
      for (int j = 0; j < 3; j++) {
        int u = t + j * 256;
        pw[j] = *(const bf16x8*)(wBase + (kb + 1) * 12288 + u * 8);
      }
    }

    // compute current tile from LDS
    const int arow = wr * 16 + l16;
#pragma unroll
    for (int kh = 0; kh < 2; kh++) {
      bf16x8 af = *(const bf16x8*)((const char*)&Ab[cur][0] + arow * 128 +
                                   ((kh * 64 + quad * 16) ^ ((arow & 7) << 4)));
#pragma unroll
      for (int j = 0; j < 3; j++) {
        const int coll = (wc * 3 + j) * 16 + l16;
        bf16x8 wf = *(const bf16x8*)((const char*)&Wb[cur][0] + coll * 128 +
                                     ((kh * 64 + quad * 16) ^ ((coll & 7) << 4)));
        acc[j] = __builtin_amdgcn_mfma_f32_16x16x32_bf16(af, wf, acc[j], 0, 0, 0);
      }
    }

    // stage next tile into the other buffer
    if (kb < 15) {
      const int nb = cur ^ 1;
#pragma unroll
      for (int j = 0; j < 2; j++) {
        int u = t + j * 256;
        int row = u >> 4, kq = u & 15;
        unsigned int lo = (unsigned int)f2b(pa[j][0]) | ((unsigned int)f2b(pa[j][1]) << 16);
        unsigned int hi = (unsigned int)f2b(pa[j][2]) | ((unsigned int)f2b(pa[j][3]) << 16);
        uint2 pk; pk.x = lo; pk.y = hi;
        *(uint2*)((char*)&Ab[nb][0] + row * 128 + ((kq * 8) ^ ((row & 7) << 4))) = pk;
      }
#pragma unroll
      for (int j = 0; j < 3; j++) {
        int u = t + j * 256;
        int coll = u >> 3, kd8 = u & 7;
        *(bf16x8*)((char*)&Wb[nb][0] + coll * 128 + ((kd8 ^ (coll & 7)) << 4)) = pw[j];
      }
      __syncthreads();
    }
  }

  // ---- epilogue: Q,K natural stores ----
#pragma unroll
  for (int j = 0; j < 3; j++) {
    int gc = ch * 96 + (wc * 3 + j) * 16 + l16;
    if (gc < 128) {                               // uniform per (wave,j)
      int m  = gc >> 6, cm = gc & 63;
#pragma unroll
      for (int r = 0; r < 4; r++) {
        int row = rt * 32 + wr * 16 + quad * 4 + r;   // C/D: row = quad*4+reg, col = l16
        qkv[(size_t)m * QKVSZ + (size_t)row * HD + cm] = f2b(acc[j][r]);
      }
    }
  }

  // ---- epilogue: V -> LDS transpose -> vT[b][h][s] coalesced store ----
  if (ch == 1) {
    __syncthreads();                               // LDS free after last MFMA
    unsigned short* Vsh = (unsigned short*)&Ab[0][0];   // 64 h x 40 pitch = 5120 shorts
#pragma unroll
    for (int j = 0; j < 3; j++) {
      int gc = 96 + (wc * 3 + j) * 16 + l16;
      if (gc >= 128) {
        int h = gc - 128;
#pragma unroll
        for (int r = 0; r < 4; r++)
          Vsh[h * 40 + wr * 16 + quad * 4 + r] = f2b(acc[j][r]);
      }
    }
    __syncthreads();
    int h  = t >> 2;
    int sq = (t & 3) * 8;
    int row0 = rt * 32;
    int b    = row0 >> 11;
    int seq0 = row0 & 2047;
    bf16x8 vv = *(const bf16x8*)(Vsh + h * 40 + sq);
    *(bf16x8*)(qkv + 2 * (size_t)QKVSZ + ((size_t)(b * 64 + h)) * SEQ + seq0 + sq) = vv;
  }
}

// ---------------- Split-K flash attention: 1 wave/block, 16 q-rows ----------------
// grid.x = 192: idx<128 -> (qt=idx, c=0); idx>=128 -> (qt=idx-64, c=1)
// qt>=64 splits its kdiag+1 tiles into two ~equal chunks (balanced tail).
// K LDS [key][d], Vt LDS [h][key] (from pre-transposed vT), P [q][key]:
// all 128B-row XOR-swizzled -> conflict-free b128 staging and fragment reads.
__global__ __launch_bounds__(64, 2) void attn_split(const unsigned short* __restrict__ qkv,
                                                    float* __restrict__ part,
                                                    float* __restrict__ out) {
  __shared__ __align__(16) unsigned short Ksh[64 * 64];   // 8 KB
  __shared__ __align__(16) unsigned short Vt[64 * 64];    // 8 KB
  __shared__ __align__(16) unsigned short Psh[16 * 64];   // 4 KB

  const int t = threadIdx.x;        // one wave
  const int quad = t >> 4;
  const int l16  = t & 15;
  const int idx = blockIdx.x;
  const int b   = blockIdx.y;
  const int qt  = (idx < 128) ? idx : (idx - 64);
  const int c   = (idx < 128) ? 0 : 1;
  const int q0  = qt * 16;
  const int kdiag = qt >> 2;                      // global diagonal tile
  int t0, t1;
  if (qt < 64) { t0 = 0; t1 = kdiag; }
  else {
    int n0 = (kdiag + 2) >> 1;                    // ceil((kdiag+1)/2)
    t0 = c ? n0 : 0;
    t1 = c ? kdiag : (n0 - 1);
  }

  const unsigned short* qg = qkv;
  const unsigned short* kg = qkv + QKVSZ;
  const unsigned short* vg = qkv + 2 * QKVSZ;     // vT[b][h][s]

  const unsigned short* qptr = qg + ((size_t)(b * SEQ + q0 + l16)) * HD + quad * 8;
  const bf16x8 qf0 = *(const bf16x8*)qptr;        // d 0..31
  const bf16x8 qf1 = *(const bf16x8*)(qptr + 32); // d 32..63

  f32x4 o0 = {0,0,0,0}, o1 = {0,0,0,0}, o2 = {0,0,0,0}, o3 = {0,0,0,0};
  float mst[4] = {-INFINITY, -INFINITY, -INFINITY, -INFINITY};
  float lst[4] = {0.f, 0.f, 0.f, 0.f};
  const float sc = 0.125f * 1.44269504088896f;    // 1/sqrt(64) * log2(e)

  // prologue: prefetch tile t0 into registers
  bf16x8 kpre[8], vpre[8];
  {
    const unsigned short* kgb = kg + ((size_t)(b * SEQ + t0 * 64)) * HD;
#pragma unroll
    for (int i = 0; i < 8; i++) {
      int u = t + i * 64;
      kpre[i] = *(const bf16x8*)(kgb + (size_t)(u >> 3) * HD + (u & 7) * 8);
      vpre[i] = *(const bf16x8*)(vg + ((size_t)(b * 64 + (u >> 3))) * SEQ + t0 * 64 + (u & 7) * 8);
    }
  }

  for (int kb = t0; kb <= t1; kb++) {
    // stage prefetched tile into LDS (swizzled b128 writes, conflict-free)
#pragma unroll
    for (int i = 0; i < 8; i++) {
      int u = t + i * 64;
      int row = u >> 3, sb = (u & 7) * 16;
      *(bf16x8*)((char*)Ksh + row * 128 + (sb ^ ((row & 7) << 4))) = kpre[i];
      *(bf16x8*)((char*)Vt  + row * 128 + (sb ^ ((row & 7) << 4))) = vpre[i];
    }
    __syncthreads();

    // prefetch next tile
    if (kb < t1) {
      const unsigned short* kgb = kg + ((size_t)(b * SEQ + (kb + 1) * 64)) * HD;
#pragma unroll
      for (int i = 0; i < 8; i++) {
        int u = t + i * 64;
        kpre[i] = *(const bf16x8*)(kgb + (size_t)(u >> 3) * HD + (u & 7) * 8);
        vpre[i] = *(const bf16x8*)(vg + ((size_t)(b * 64 + (u >> 3))) * SEQ + (kb + 1) * 64 + (u & 7) * 8);
      }
    }

    // S = Q K^T  (4 ktiles of 16 keys)
    f32x4 s[4];
#pragma unroll
    for (int kt = 0; kt < 4; kt++) {
      int row = kt * 16 + l16;
      bf16x8 kf0 = *(const bf16x8*)((char*)Ksh + row * 128 + ((quad * 16) ^ ((row & 7) << 4)));
      bf16x8 kf1 = *(const bf16x8*)((char*)Ksh + row * 128 + ((64 + quad * 16) ^ ((row & 7) << 4)));
      f32x4 z = {0.f, 0.f, 0.f, 0.f};
      z = __builtin_amdgcn_mfma_f32_16x16x32_bf16(qf0, kf0, z, 0, 0, 0);
      z = __builtin_amdgcn_mfma_f32_16x16x32_bf16(qf1, kf1, z, 0, 0, 0);
      s[kt] = z;
    }

    // scale; causal mask only on the diagonal tile
    if (kb == kdiag) {
#pragma unroll
      for (int r = 0; r < 4; r++) {
        int rowg = q0 + quad * 4 + r;
#pragma unroll
        for (int kt = 0; kt < 4; kt++) {
          int col = kb * 64 + kt * 16 + l16;
          float v = s[kt][r] * sc;
          s[kt][r] = (col > rowg) ? -INFINITY : v;
        }
      }
    } else {
#pragma unroll
      for (int r = 0; r < 4; r++)
#pragma unroll
        for (int kt = 0; kt < 4; kt++) s[kt][r] *= sc;
    }

    // online softmax (reduce across the 16-lane col group)
    float alpha[4];
#pragma unroll
    for (int r = 0; r < 4; r++) {
      float mx = fmaxf(fmaxf(s[0][r], s[1][r]), fmaxf(s[2][r], s[3][r]));
#pragma unroll
      for (int off = 1; off < 16; off <<= 1) mx = fmaxf(mx, __shfl_xor(mx, off, 64));
      float mnew = fmaxf(mst[r], mx);
      alpha[r] = exp2f(mst[r] - mnew);
      mst[r] = mnew;
    }
#pragma unroll
    for (int r = 0; r < 4; r++) {
      float sm = 0.f;
#pragma unroll
      for (int kt = 0; kt < 4; kt++) {
        float p = exp2f(s[kt][r] - mst[r]);
        s[kt][r] = p;
        sm += p;
      }
#pragma unroll
      for (int off = 1; off < 16; off <<= 1) sm += __shfl_xor(sm, off, 64);
      lst[r] = lst[r] * alpha[r] + sm;
    }
#pragma unroll
    for (int r = 0; r < 4; r++) { o0[r] *= alpha[r]; o1[r] *= alpha[r]; o2[r] *= alpha[r]; o3[r] *= alpha[r]; }

    // P (C-layout) -> LDS bf16 (swizzled)
#pragma unroll
    for (int kt = 0; kt < 4; kt++)
#pragma unroll
      for (int r = 0; r < 4; r++) {
        int row = quad * 4 + r;
        *(unsigned short*)((char*)Psh + row * 128 + ((kt * 32 + l16 * 2) ^ ((row & 7) << 4))) = f2b(s[kt][r]);
      }
    __syncthreads();

    // O += P V
#pragma unroll
    for (int kc = 0; kc < 2; kc++) {
      bf16x8 pf = *(const bf16x8*)((char*)Psh + l16 * 128 + ((kc * 64 + quad * 16) ^ ((l16 & 7) << 4)));
#pragma unroll
      for (int ht = 0; ht < 1; ht++) {}           // (kept simple: unrolled below)
      {
        int r0 = 0 * 16 + l16, r1 = 1 * 16 + l16, r2 = 2 * 16 + l16, r3 = 3 * 16 + l16;
        bf16x8 vf0 = *(const bf16x8*)((char*)Vt + r0 * 128 + ((kc * 64 + quad * 16) ^ ((r0 & 7) << 4)));
        bf16x8 vf1 = *(const bf16x8*)((char*)Vt + r1 * 128 + ((kc * 64 + quad * 16) ^ ((r1 & 7) << 4)));
        bf16x8 vf2 = *(const bf16x8*)((char*)Vt + r2 * 128 + ((kc * 64 + quad * 16) ^ ((r2 & 7) << 4)));
        bf16x8 vf3 = *(const bf16x8*)((char*)Vt + r3 * 128 + ((kc * 64 + quad * 16) ^ ((r3 & 7) << 4)));
        o0 = __builtin_amdgcn_mfma_f32_16x16x32_bf16(pf, vf0, o0, 0, 0, 0);
        o1 = __builtin_amdgcn_mfma_f32_16x16x32_bf16(pf, vf1, o1, 0, 0, 0);
        o2 = __builtin_amdgcn_mfma_f32_16x16x32_bf16(pf, vf2, o2, 0, 0, 0);
        o3 = __builtin_amdgcn_mfma_f32_16x16x32_bf16(pf, vf3, o3, 0, 0, 0);
      }
    }
    __syncthreads();
  }

  if (qt < 64) {  // single chunk: finalize directly
#pragma unroll
    for (int r = 0; r < 4; r++) {
      float inv = 1.f / lst[r];
      int rowg = q0 + quad * 4 + r;
      size_t ob = ((size_t)(b * SEQ + rowg)) * HD + l16;
      out[ob + 0]  = o0[r] * inv;
      out[ob + 16] = o1[r] * inv;
      out[ob + 32] = o2[r] * inv;
      out[ob + 48] = o3[r] * inv;
    }
  } else {        // write unnormalized partial + (m,l)
    float* ps = part + ((size_t)((b * 64 + (qt - 64)) * 2 + c)) * PSLOT;
#pragma unroll
    for (int r = 0; r < 4; r++) {
      int row = quad * 4 + r;
      ps[row * 64 + 0  + l16] = o0[r];
      ps[row * 64 + 16 + l16] = o1[r];
      ps[row * 64 + 32 + l16] = o2[r];
      ps[row * 64 + 48 + l16] = o3[r];
      if (l16 == 0) {
        ps[1024 + row] = mst[r];
        ps[1040 + row] = lst[r];
      }
    }
  }
}

// ---------------- merge two partials for qt in [64,128) ----------------
__global__ __launch_bounds__(64) void attn_merge(const float* __restrict__ part,
                                                 float* __restrict__ out) {
  const int h  = threadIdx.x;       // 0..63
  const int qx = blockIdx.x;        // 0..63 -> qt = 64+qx
  const int b  = blockIdx.y;
  const float* p0 = part + ((size_t)((b * 64 + qx) * 2 + 0)) * PSLOT;
  const float* p1 = p0 + PSLOT;
#pragma unroll 4
  for (int r = 0; r < 16; r++) {
    float m0 = p0[1024 + r], l0 = p0[1040 + r];
    float m1 = p1[1024 + r], l1 = p1[1040 + r];
    float M  = fmaxf(m0, m1);
    float e0 = exp2f(m0 - M), e1 = exp2f(m1 - M);
    float L  = l0 * e0 + l1 * e1;
    float o  = (p0[r * 64 + h] * e0 + p1[r * 64 + h] * e1) / L;
    out[((size_t)(b * SEQ + (64 + qx) * 16 + r)) * HD + h] = o;
  }
}

extern "C" void kernel_launch(void* const* d_in, const int* in_sizes, int n_in,
                              void* d_out, int out_size, void* d_ws, size_t ws_size,
                              hipStream_t stream) {
  const float* emb = (const float*)d_in[0];
  const float* wq  = (const float*)d_in[1];
  const float* wk  = (const float*)d_in[2];
  const float* wv  = (const float*)d_in[3];
  unsigned short* ws  = (unsigned short*)d_ws;
  unsigned short* wt  = ws;              // 196608 bf16
  unsigned short* qkv = ws + WTSZ;       // q,k natural + vT  (3 x 1048576 bf16)
  float* part = (float*)(ws + WTSZ + 3 * QKVSZ);   // 1024 slots x 1088 fp32 = 4.25 MB

  hipLaunchKernelGGL(wtrans_kernel,   dim3(WTSZ / 256), dim3(256), 0, stream, wq, wk, wv, wt);
  hipLaunchKernelGGL(qkv_proj_kernel, dim3(1024),       dim3(256), 0, stream, emb, wt, qkv);
  hipLaunchKernelGGL(attn_split,      dim3(192, 8),     dim3(64),  0, stream, qkv, part, (float*)d_out);
  hipLaunchKernelGGL(attn_merge,      dim3(64, 8),      dim3(64),  0, stream, part, (float*)d_out);
}